// Round 6
// baseline (297.736 us; speedup 1.0000x reference)
//
#include <hip/hip_runtime.h>

// TemplatePointwiseAttention on MI355X (gfx950) — round 11
// B=1, T=4, I=J=256 (P=65536 pixels), C_in=128, heads=4, att_c=64.
//
// Algebraic fusion (unchanged):
//   scores[t,p,h] = z[p] . M_h . a_t[p],   M_h = sum_{n%4==h} Wq[n](x)Wk[n] / sqrt(128)
//   out[p,m]      = sum_h Abar_h[p] . P_h[m] + bo[m],
//                   Abar_h[p] = sum_t softmax_w[t,p,h] * a_t[p]
//
// Round-11 = round-10 (measured 277.9; score 78.6, out ~40) with ONE delta:
// 1024-thread workgroups.  r10 post-mortem: both kernels are latency-bound
// at 8 waves/CU (LDS -> 1 WG/CU, 512 thr); bank conflicts proved benign
// (exactly 1 cyc per ds_read_b128 across 3 different layouts).  Same LDS,
// same per-wave math; each wave does 16 px (score: it-loop deleted; out:
// mt-dim deleted).  16 waves/CU = 4/SIMD; __launch_bounds__(1024,4) caps
// VGPR at 128 = what both kernels already used.

#define PIX 65536

typedef __attribute__((ext_vector_type(8))) short s8v;      // bf16 x8 MFMA frag
typedef __attribute__((ext_vector_type(4))) float f4v;      // fp32 x4 acc
typedef __attribute__((ext_vector_type(4))) unsigned int u4v;
typedef __attribute__((ext_vector_type(4))) float fl4;

__device__ __forceinline__ unsigned short f2bf(float x) {
    unsigned int u = __float_as_uint(x);
    u = (u + 0x7FFFu + ((u >> 16) & 1u)) >> 16;   // round-to-nearest-even
    return (unsigned short)u;
}
__device__ __forceinline__ float bf2fs(short v) {
    return __uint_as_float(((unsigned int)(unsigned short)v) << 16);
}

// hw packed f32->bf16 (RNE); low16 = src0, high16 = src1
__device__ __forceinline__ unsigned int cvtpk(float lo, float hi) {
    unsigned int r;
    asm("v_cvt_pk_bf16_f32 %0, %1, %2" : "=v"(r) : "v"(lo), "v"(hi));
    return r;
}

__device__ __forceinline__ s8v pack8(fl4 d0, fl4 d1) {
    union { u4v u; s8v s; } cv;
    cv.u[0] = cvtpk(d0[0], d0[1]);
    cv.u[1] = cvtpk(d0[2], d0[3]);
    cv.u[2] = cvtpk(d1[0], d1[1]);
    cv.u[3] = cvtpk(d1[2], d1[3]);
    return cv.s;
}

__device__ __forceinline__ float bflo(unsigned int u) { return __uint_as_float(u << 16); }
__device__ __forceinline__ float bfhi(unsigned int u) { return __uint_as_float(u & 0xffff0000u); }

// Prologue: Mcat[n=h*128+k2][k1] = (1/sqrt128) sum_c Wq[c*4+h][k1] Wk[c*4+h][k2]
//           Pcat[m][kk=h*128+k]  = sum_c Wo[m][c*4+h] Wv[c*4+h][k]
__global__ __launch_bounds__(256) void build_weights(
        const float* __restrict__ Wq, const float* __restrict__ Wk,
        const float* __restrict__ Wv, const float* __restrict__ Wo,
        unsigned short* __restrict__ mcat, unsigned short* __restrict__ pcat) {
    int b = blockIdx.x;
    if (b < 256) {
        int idx = b * 256 + threadIdx.x;
        int n = idx >> 7, k1 = idx & 127;
        int h = n >> 7, k2 = n & 127;
        float s = 0.f;
        #pragma unroll 8
        for (int c = 0; c < 64; c++) {
            int r = c * 4 + h;
            s += Wq[r * 128 + k1] * Wk[r * 128 + k2];
        }
        mcat[idx] = f2bf(s * 0.088388347648318447f);
    } else {
        int idx = (b - 256) * 256 + threadIdx.x;
        int m = idx >> 9, kk = idx & 511;
        int h = kk >> 7, k = kk & 127;
        float s = 0.f;
        #pragma unroll 8
        for (int c = 0; c < 64; c++) {
            int r = c * 4 + h;
            s += Wo[m * 256 + r] * Wv[r * 128 + k];
        }
        pcat[idx] = f2bf(s);
    }
}

// ======================= Kernel S: scores + softmax =======================
// Grid 256 x 1024 threads (16 waves), 16 px per wave.
// LDS: mcat [512][136] (stride 68 words = 4 mod 32; rows 16B-aligned).
// Staged once, one barrier, then free-run.
#define S_USH (512 * 136)                        // 69632 ush = 139,264 B

__global__ __launch_bounds__(1024, 4) void score_kernel(
    const float* __restrict__ z2d, const float* __restrict__ t2d,
    const unsigned short* __restrict__ mcat, float* __restrict__ wbuf) {

    __shared__ unsigned short sm[S_USH];
    const int tid = threadIdx.x;

    // stage mcat (coalesced 16B units) — once per WG (16 units per 128-ush row)
    #pragma unroll
    for (int i = 0; i < 8; i++) {
        int g8 = i * 1024 + tid;                 // 16B-unit index, 8192 total
        int row = g8 >> 4, c8 = g8 & 15;
        *(u4v*)&sm[row * 136 + c8 * 8] = *(const u4v*)(mcat + (size_t)g8 * 8);
    }
    __syncthreads();   // the only barrier

    const int wv = tid >> 6, lane = tid & 63, quad = lane >> 4, l15 = lane & 15;
    const int p = blockIdx.x * 256 + wv * 16 + l15;   // this lane's pixel

    // z fragments: B-operand (col = pixel = l15, k1 = ks*32 + quad*8 + j)
    s8v za[4];
    {
        const float* zp = z2d + (size_t)p * 128 + quad * 8;
        #pragma unroll
        for (int ks = 0; ks < 4; ks++)
            za[ks] = pack8(*(const fl4*)(zp + ks * 32), *(const fl4*)(zp + ks * 32 + 4));
    }
    // a_t in C-layout pattern: lane (quad,l15) holds a_t[p][k2=cb*16+quad*4+{0..3}]
    // packed bf16 (2 u32 per (t,cb)).
    unsigned int a2[4][8][2];
    #pragma unroll
    for (int t = 0; t < 4; t++) {
        const float* ap = t2d + ((size_t)t * PIX + p) * 128 + quad * 4;
        #pragma unroll
        for (int cb = 0; cb < 8; cb++) {
            const fl4 v = *(const fl4*)(ap + cb * 16);
            a2[t][cb][0] = cvtpk(v[0], v[1]);
            a2[t][cb][1] = cvtpk(v[2], v[3]);
        }
    }

    #pragma unroll
    for (int h = 0; h < 4; h++) {
        float ps[4] = {0.f, 0.f, 0.f, 0.f};
        #pragma unroll
        for (int cb = 0; cb < 8; cb++) {
            // u^T tile: C[row = k2 = cb*16+quad*4+r][col = pixel l15]
            f4v u = {0.f, 0.f, 0.f, 0.f};
            #pragma unroll
            for (int ks = 0; ks < 4; ks++) {
                // A-frag row = h*128 + cb*16 + l15, k1 = ks*32 + quad*8
                const s8v a = *(const s8v*)&sm[(h * 128 + cb * 16 + l15) * 136 +
                                               ks * 32 + quad * 8];
                u = __builtin_amdgcn_mfma_f32_16x16x32_bf16(a, za[ks], u, 0, 0, 0);
            }
            // in-lane partial dot over the 4 k2 rows this lane holds
            #pragma unroll
            for (int t = 0; t < 4; t++) {
                ps[t] += u[0] * bflo(a2[t][cb][0]) + u[1] * bfhi(a2[t][cb][0])
                       + u[2] * bflo(a2[t][cb][1]) + u[3] * bfhi(a2[t][cb][1]);
            }
        }
        // reduce across the 4 quads (same l15) -> full score in every lane
        #pragma unroll
        for (int t = 0; t < 4; t++) {
            ps[t] += __shfl_xor(ps[t], 16);
            ps[t] += __shfl_xor(ps[t], 32);
        }
        const float mx = fmaxf(fmaxf(ps[0], ps[1]), fmaxf(ps[2], ps[3]));
        float e[4], sum = 0.f;
        #pragma unroll
        for (int t = 0; t < 4; t++) { e[t] = __expf(ps[t] - mx); sum += e[t]; }
        const float inv = 1.f / sum;
        if (quad == 0) {
            #pragma unroll
            for (int t = 0; t < 4; t++)
                wbuf[(size_t)(h * 4 + t) * PIX + p] = e[t] * inv;
        }
    }
}

// ======================= Kernel O: Abar + output GEMM =======================
// Grid 256 x 1024 threads (16 waves), 16 px per wave.
// LDS: pcat [128][520] (stride 260 words = 4 mod 32)
#define O_USH (128 * 520)                        // 66560 ush = 133,120 B

__global__ __launch_bounds__(1024, 4) void out_kernel(
    const float* __restrict__ t2d, const unsigned short* __restrict__ pcat,
    const float* __restrict__ wbuf, const float* __restrict__ bo,
    float* __restrict__ out) {

    __shared__ unsigned short sm[O_USH];
    const int tid = threadIdx.x;

    // stage pcat — once per WG (512-ush row = 64 x 16B units)
    #pragma unroll
    for (int i = 0; i < 8; i++) {
        int g8 = i * 1024 + tid;                 // 8192 x 16B
        int row = g8 >> 6, c8 = g8 & 63;
        *(u4v*)&sm[row * 520 + c8 * 8] = *(const u4v*)(pcat + (size_t)g8 * 8);
    }
    __syncthreads();   // the only barrier

    const int wv = tid >> 6, lane = tid & 63, quad = lane >> 4, l15 = lane & 15;
    const int p0 = blockIdx.x * 256 + wv * 16;   // 16 px per wave
    const int p = p0 + l15;

    // softmax weights for this wave's 16 pixels
    float wgt[4][4];                             // [t][h]
    #pragma unroll
    for (int h = 0; h < 4; h++)
        #pragma unroll
        for (int t = 0; t < 4; t++)
            wgt[t][h] = wbuf[(size_t)(h * 4 + t) * PIX + p];

    f4v acc[8];
    #pragma unroll
    for (int ct = 0; ct < 8; ct++) acc[ct] = (f4v){0.f, 0.f, 0.f, 0.f};

    #pragma unroll
    for (int ks = 0; ks < 4; ks++) {             // K-within-head, outer
        // t2d slices for this ks (4 t), fp32 -> bf16 regs
        s8v ab[4];
        #pragma unroll
        for (int t = 0; t < 4; t++) {
            const float* ap = t2d + ((size_t)t * PIX + p) * 128 + ks * 32 + quad * 8;
            ab[t] = pack8(*(const fl4*)ap, *(const fl4*)(ap + 4));
        }
        #pragma unroll
        for (int h = 0; h < 4; h++) {
            // Abar A-frag in registers
            s8v af;
            #pragma unroll
            for (int j = 0; j < 8; j++) {
                float v = wgt[0][h] * bf2fs(ab[0][j])
                        + wgt[1][h] * bf2fs(ab[1][j])
                        + wgt[2][h] * bf2fs(ab[2][j])
                        + wgt[3][h] * bf2fs(ab[3][j]);
                af[j] = (short)f2bf(v);
            }
            #pragma unroll
            for (int ct = 0; ct < 8; ct++) {
                const s8v b = *(const s8v*)&sm[(ct * 16 + l15) * 520
                                               + h * 128 + ks * 32 + quad * 8];
                acc[ct] = __builtin_amdgcn_mfma_f32_16x16x32_bf16(af, b, acc[ct], 0, 0, 0);
            }
        }
    }

    // epilogue: bias + fp32 store (C row = pixel p0+quad*4+r, col = ct*16+l15)
    #pragma unroll
    for (int ct = 0; ct < 8; ct++) {
        const float bb = bo[ct * 16 + l15];
        #pragma unroll
        for (int r = 0; r < 4; r++)
            out[(size_t)(p0 + quad * 4 + r) * 128 + ct * 16 + l15] = acc[ct][r] + bb;
    }
}

extern "C" void kernel_launch(void* const* d_in, const int* in_sizes, int n_in,
                              void* d_out, int out_size, void* d_ws, size_t ws_size,
                              hipStream_t stream) {
    const float* z2d = (const float*)d_in[0];
    const float* t2d = (const float*)d_in[1];
    const float* Wq  = (const float*)d_in[2];
    const float* Wk  = (const float*)d_in[3];
    const float* Wv  = (const float*)d_in[4];
    const float* Wo  = (const float*)d_in[5];
    const float* bo  = (const float*)d_in[6];

    unsigned short* mcat = (unsigned short*)d_ws;          // 512*128 bf16 = 128 KB
    unsigned short* pcat = mcat + 512 * 128;               // 128*512 bf16 = 128 KB
    float* wbuf = (float*)(pcat + 128 * 512);              // 16*65536 fp32 = 4 MB

    build_weights<<<512, 256, 0, stream>>>(Wq, Wk, Wv, Wo, mcat, pcat);
    score_kernel<<<256, 1024, 0, stream>>>(z2d, t2d, mcat, wbuf);
    out_kernel<<<256, 1024, 0, stream>>>(t2d, pcat, wbuf, bo, (float*)d_out);
}

// Round 7
// 277.458 us; speedup vs baseline: 1.0731x; 1.0731x over previous
//
#include <hip/hip_runtime.h>

// TemplatePointwiseAttention on MI355X (gfx950) — round 12
// B=1, T=4, I=J=256 (P=65536 pixels), C_in=128, heads=4, att_c=64.
//
// Algebraic fusion (unchanged):
//   scores[t,p,h] = z[p] . M_h . a_t[p],   M_h = sum_{n%4==h} Wq[n](x)Wk[n] / sqrt(128)
//   out[p,m]      = sum_h Abar_h[p] . P_h[m] + bo[m],
//                   Abar_h[p] = sum_t softmax_w[t,p,h] * a_t[p]
//
// Round-12 = round-10 (277.9; score 78.6, out ~40) with ONE delta in score:
// loop interchange (cb outer, h inner).  r11 post-mortem: out_kernel moves
// the same traffic at 4.2 TB/s vs score's 2.1 with identical occupancy/LDS;
// the difference is score's monolithic 40-load a2 prologue (64 live VGPRs,
// serialized load->waitcnt->cvtpk rounds) vs out's interleaved load/consume.
// Here a2 is loaded per-cb (4 loads, 8 regs live) inside the main loop;
// per cb the 4 h-chains (4 MFMAs each) are independent -> real ILP.
// #pragma unroll 2 on cb so the compiler pipelines without re-hoisting all
// loads.  Indexing byte-identical to r10 (verified); only accumulation
// order changes.  out_kernel verbatim r10 (measured ~40 us).

#define PIX 65536

typedef __attribute__((ext_vector_type(8))) short s8v;      // bf16 x8 MFMA frag
typedef __attribute__((ext_vector_type(4))) float f4v;      // fp32 x4 acc
typedef __attribute__((ext_vector_type(4))) unsigned int u4v;
typedef __attribute__((ext_vector_type(4))) float fl4;

__device__ __forceinline__ unsigned short f2bf(float x) {
    unsigned int u = __float_as_uint(x);
    u = (u + 0x7FFFu + ((u >> 16) & 1u)) >> 16;   // round-to-nearest-even
    return (unsigned short)u;
}
__device__ __forceinline__ float bf2fs(short v) {
    return __uint_as_float(((unsigned int)(unsigned short)v) << 16);
}

// hw packed f32->bf16 (RNE); low16 = src0, high16 = src1
__device__ __forceinline__ unsigned int cvtpk(float lo, float hi) {
    unsigned int r;
    asm("v_cvt_pk_bf16_f32 %0, %1, %2" : "=v"(r) : "v"(lo), "v"(hi));
    return r;
}

__device__ __forceinline__ s8v pack8(fl4 d0, fl4 d1) {
    union { u4v u; s8v s; } cv;
    cv.u[0] = cvtpk(d0[0], d0[1]);
    cv.u[1] = cvtpk(d0[2], d0[3]);
    cv.u[2] = cvtpk(d1[0], d1[1]);
    cv.u[3] = cvtpk(d1[2], d1[3]);
    return cv.s;
}

__device__ __forceinline__ float bflo(unsigned int u) { return __uint_as_float(u << 16); }
__device__ __forceinline__ float bfhi(unsigned int u) { return __uint_as_float(u & 0xffff0000u); }

// Prologue: Mcat[n=h*128+k2][k1] = (1/sqrt128) sum_c Wq[c*4+h][k1] Wk[c*4+h][k2]
//           Pcat[m][kk=h*128+k]  = sum_c Wo[m][c*4+h] Wv[c*4+h][k]
__global__ __launch_bounds__(256) void build_weights(
        const float* __restrict__ Wq, const float* __restrict__ Wk,
        const float* __restrict__ Wv, const float* __restrict__ Wo,
        unsigned short* __restrict__ mcat, unsigned short* __restrict__ pcat) {
    int b = blockIdx.x;
    if (b < 256) {
        int idx = b * 256 + threadIdx.x;
        int n = idx >> 7, k1 = idx & 127;
        int h = n >> 7, k2 = n & 127;
        float s = 0.f;
        #pragma unroll 8
        for (int c = 0; c < 64; c++) {
            int r = c * 4 + h;
            s += Wq[r * 128 + k1] * Wk[r * 128 + k2];
        }
        mcat[idx] = f2bf(s * 0.088388347648318447f);
    } else {
        int idx = (b - 256) * 256 + threadIdx.x;
        int m = idx >> 9, kk = idx & 511;
        int h = kk >> 7, k = kk & 127;
        float s = 0.f;
        #pragma unroll 8
        for (int c = 0; c < 64; c++) {
            int r = c * 4 + h;
            s += Wo[m * 256 + r] * Wv[r * 128 + k];
        }
        pcat[idx] = f2bf(s);
    }
}

// ======================= Kernel S: scores + softmax =======================
// Grid 256 x 512 threads (8 waves), 32 px per wave (2 its of 16).
// LDS: mcat [512][136] (stride 68 words = 4 mod 32; rows 16B-aligned).
// Staged once, one barrier, then free-run with interleaved loads.
#define S_USH (512 * 136)                        // 69632 ush = 139,264 B

__global__ __launch_bounds__(512, 2) void score_kernel(
    const float* __restrict__ z2d, const float* __restrict__ t2d,
    const unsigned short* __restrict__ mcat, float* __restrict__ wbuf) {

    __shared__ unsigned short sm[S_USH];
    const int tid = threadIdx.x;

    // stage mcat (coalesced 16B units) — once per WG (16 units per 128-ush row)
    #pragma unroll
    for (int i = 0; i < 16; i++) {
        int g8 = i * 512 + tid;                  // 16B-unit index, 8192 total
        int row = g8 >> 4, c8 = g8 & 15;
        *(u4v*)&sm[row * 136 + c8 * 8] = *(const u4v*)(mcat + (size_t)g8 * 8);
    }
    __syncthreads();   // the only barrier

    const int wv = tid >> 6, lane = tid & 63, quad = lane >> 4, l15 = lane & 15;

    for (int it = 0; it < 2; it++) {
        const int p = blockIdx.x * 256 + (wv * 2 + it) * 16 + l15;

        // z fragments: B-operand (col = pixel = l15, k1 = ks*32 + quad*8 + j)
        s8v za[4];
        {
            const float* zp = z2d + (size_t)p * 128 + quad * 8;
            #pragma unroll
            for (int ks = 0; ks < 4; ks++)
                za[ks] = pack8(*(const fl4*)(zp + ks * 32), *(const fl4*)(zp + ks * 32 + 4));
        }

        float ps[4][4];                          // [h][t] score accumulators
        #pragma unroll
        for (int h = 0; h < 4; h++)
            #pragma unroll
            for (int t = 0; t < 4; t++) ps[h][t] = 0.f;

        const float* apb = t2d + (size_t)p * 128 + quad * 4;

        #pragma unroll 2
        for (int cb = 0; cb < 8; cb++) {
            // a_t slice for this cb only: lane holds a_t[p][k2=cb*16+quad*4+{0..3}]
            unsigned int a2[4][2];
            #pragma unroll
            for (int t = 0; t < 4; t++) {
                const fl4 v = *(const fl4*)(apb + (size_t)t * (PIX * 128) + cb * 16);
                a2[t][0] = cvtpk(v[0], v[1]);
                a2[t][1] = cvtpk(v[2], v[3]);
            }
            // u^T tiles for all 4 heads: 4 independent 4-MFMA chains
            #pragma unroll
            for (int h = 0; h < 4; h++) {
                f4v u = {0.f, 0.f, 0.f, 0.f};
                #pragma unroll
                for (int ks = 0; ks < 4; ks++) {
                    // A-frag row = h*128 + cb*16 + l15, k1 = ks*32 + quad*8
                    const s8v a = *(const s8v*)&sm[(h * 128 + cb * 16 + l15) * 136 +
                                                   ks * 32 + quad * 8];
                    u = __builtin_amdgcn_mfma_f32_16x16x32_bf16(a, za[ks], u, 0, 0, 0);
                }
                // in-lane partial dot over the 4 k2 rows this lane holds
                #pragma unroll
                for (int t = 0; t < 4; t++) {
                    ps[h][t] += u[0] * bflo(a2[t][0]) + u[1] * bfhi(a2[t][0])
                              + u[2] * bflo(a2[t][1]) + u[3] * bfhi(a2[t][1]);
                }
            }
        }

        #pragma unroll
        for (int h = 0; h < 4; h++) {
            // reduce across the 4 quads (same l15) -> full score in every lane
            float s0 = ps[h][0], s1 = ps[h][1], s2 = ps[h][2], s3 = ps[h][3];
            s0 += __shfl_xor(s0, 16); s0 += __shfl_xor(s0, 32);
            s1 += __shfl_xor(s1, 16); s1 += __shfl_xor(s1, 32);
            s2 += __shfl_xor(s2, 16); s2 += __shfl_xor(s2, 32);
            s3 += __shfl_xor(s3, 16); s3 += __shfl_xor(s3, 32);
            const float mx = fmaxf(fmaxf(s0, s1), fmaxf(s2, s3));
            const float e0 = __expf(s0 - mx), e1 = __expf(s1 - mx);
            const float e2 = __expf(s2 - mx), e3 = __expf(s3 - mx);
            const float inv = 1.f / (e0 + e1 + e2 + e3);
            if (quad == 0) {
                float* wp = wbuf + (size_t)h * 4 * PIX + p;
                wp[0 * PIX] = e0 * inv; wp[1 * PIX] = e1 * inv;
                wp[2 * PIX] = e2 * inv; wp[3 * PIX] = e3 * inv;
            }
        }
    }
}

// ======================= Kernel O: Abar + output GEMM =======================
// (byte-identical to round-10's measured ~40 us kernel)
// LDS: pcat [128][520] (stride 260 words = 4 mod 32)
#define O_USH (128 * 520)                        // 66560 ush = 133,120 B

__global__ __launch_bounds__(512, 2) void out_kernel(
    const float* __restrict__ t2d, const unsigned short* __restrict__ pcat,
    const float* __restrict__ wbuf, const float* __restrict__ bo,
    float* __restrict__ out) {

    __shared__ unsigned short sm[O_USH];
    const int tid = threadIdx.x;

    // stage pcat — once per WG (512-ush row = 64 x 16B units)
    #pragma unroll
    for (int i = 0; i < 16; i++) {
        int g8 = i * 512 + tid;                  // 8192 x 16B
        int row = g8 >> 6, c8 = g8 & 63;
        *(u4v*)&sm[row * 520 + c8 * 8] = *(const u4v*)(pcat + (size_t)g8 * 8);
    }
    __syncthreads();   // the only barrier

    const int wv = tid >> 6, lane = tid & 63, quad = lane >> 4, l15 = lane & 15;
    const int p0 = blockIdx.x * 256 + wv * 32;   // 32 px per wave

    // softmax weights for this wave's 32 pixels
    float wgt[4][2][4];                          // [t][mt][h]
    #pragma unroll
    for (int h = 0; h < 4; h++)
        #pragma unroll
        for (int t = 0; t < 4; t++)
            #pragma unroll
            for (int mt = 0; mt < 2; mt++)
                wgt[t][mt][h] = wbuf[(size_t)(h * 4 + t) * PIX + p0 + mt * 16 + l15];

    f4v acc[2][8];
    #pragma unroll
    for (int mt = 0; mt < 2; mt++)
        #pragma unroll
        for (int ct = 0; ct < 8; ct++) acc[mt][ct] = (f4v){0.f, 0.f, 0.f, 0.f};

    #pragma unroll
    for (int ks = 0; ks < 4; ks++) {             // K-within-head, outer
        // t2d slices for this ks (4t x 2mt), fp32 -> bf16 regs
        s8v ab[4][2];
        #pragma unroll
        for (int t = 0; t < 4; t++)
            #pragma unroll
            for (int mt = 0; mt < 2; mt++) {
                const float* ap = t2d + ((size_t)t * PIX + p0 + mt * 16 + l15) * 128
                                  + ks * 32 + quad * 8;
                const fl4 d0 = *(const fl4*)ap;
                const fl4 d1 = *(const fl4*)(ap + 4);
                s8v a;
                a[0] = (short)f2bf(d0[0]); a[1] = (short)f2bf(d0[1]);
                a[2] = (short)f2bf(d0[2]); a[3] = (short)f2bf(d0[3]);
                a[4] = (short)f2bf(d1[0]); a[5] = (short)f2bf(d1[1]);
                a[6] = (short)f2bf(d1[2]); a[7] = (short)f2bf(d1[3]);
                ab[t][mt] = a;
            }
        #pragma unroll
        for (int h = 0; h < 4; h++) {
            // Abar A-frags in registers
            s8v af[2];
            #pragma unroll
            for (int mt = 0; mt < 2; mt++) {
                s8v o;
                #pragma unroll
                for (int j = 0; j < 8; j++) {
                    float v = wgt[0][mt][h] * bf2fs(ab[0][mt][j])
                            + wgt[1][mt][h] * bf2fs(ab[1][mt][j])
                            + wgt[2][mt][h] * bf2fs(ab[2][mt][j])
                            + wgt[3][mt][h] * bf2fs(ab[3][mt][j]);
                    o[j] = (short)f2bf(v);
                }
                af[mt] = o;
            }
            #pragma unroll
            for (int ct = 0; ct < 8; ct++) {
                const s8v b = *(const s8v*)&sm[(ct * 16 + l15) * 520
                                               + h * 128 + ks * 32 + quad * 8];
                acc[0][ct] = __builtin_amdgcn_mfma_f32_16x16x32_bf16(af[0], b, acc[0][ct], 0, 0, 0);
                acc[1][ct] = __builtin_amdgcn_mfma_f32_16x16x32_bf16(af[1], b, acc[1][ct], 0, 0, 0);
            }
        }
    }

    // epilogue: bias + fp32 store
    #pragma unroll
    for (int ct = 0; ct < 8; ct++) {
        const float bb = bo[ct * 16 + l15];
        #pragma unroll
        for (int mt = 0; mt < 2; mt++)
            #pragma unroll
            for (int r = 0; r < 4; r++)
                out[(size_t)(p0 + mt * 16 + quad * 4 + r) * 128 + ct * 16 + l15]
                    = acc[mt][ct][r] + bb;
    }
}

extern "C" void kernel_launch(void* const* d_in, const int* in_sizes, int n_in,
                              void* d_out, int out_size, void* d_ws, size_t ws_size,
                              hipStream_t stream) {
    const float* z2d = (const float*)d_in[0];
    const float* t2d = (const float*)d_in[1];
    const float* Wq  = (const float*)d_in[2];
    const float* Wk  = (const float*)d_in[3];
    const float* Wv  = (const float*)d_in[4];
    const float* Wo  = (const float*)d_in[5];
    const float* bo  = (const float*)d_in[6];

    unsigned short* mcat = (unsigned short*)d_ws;          // 512*128 bf16 = 128 KB
    unsigned short* pcat = mcat + 512 * 128;               // 128*512 bf16 = 128 KB
    float* wbuf = (float*)(pcat + 128 * 512);              // 16*65536 fp32 = 4 MB

    build_weights<<<512, 256, 0, stream>>>(Wq, Wk, Wv, Wo, mcat, pcat);
    score_kernel<<<256, 512, 0, stream>>>(z2d, t2d, mcat, wbuf);
    out_kernel<<<256, 512, 0, stream>>>(t2d, pcat, wbuf, bo, (float*)d_out);
}

// Round 8
// 274.927 us; speedup vs baseline: 1.0830x; 1.0092x over previous
//
#include <hip/hip_runtime.h>

// TemplatePointwiseAttention on MI355X (gfx950) — round 13
// B=1, T=4, I=J=256 (P=65536 pixels), C_in=128, heads=4, att_c=64.
//
// Algebraic fusion (unchanged):
//   scores[t,p,h] = z[p] . M_h . a_t[p],   M_h = sum_{n%4==h} Wq[n](x)Wk[n] / sqrt(128)
//   out[p,m]      = sum_h Abar_h[p] . P_h[m] + bo[m],
//                   Abar_h[p] = sum_t softmax_w[t,p,h] * a_t[p]
//
// Round-13 = round-12 (277.5; score 79.5, out ~38) with ONE delta in score:
// CODE-SIZE MINIMIZATION.  r5/r10/r12 (three different inner structures,
// ~20-25 KB unrolled bodies) all pinned at 77-79 us with every pipe idle;
// out (half the code) runs half the time at identical MFMA/traffic/occupancy.
// Theory: 8 diverged waves streaming a ~25 KB body thrash the 32 KB I-cache.
// Test: roll the it-loop (#pragma unroll 1) and the cb-pair loop; keep
// h/ks/t unrolled (ps[h][t] must stay statically indexed).  All indexing
// byte-identical to r12 (verified).  out_kernel untouched (control).

#define PIX 65536

typedef __attribute__((ext_vector_type(8))) short s8v;      // bf16 x8 MFMA frag
typedef __attribute__((ext_vector_type(4))) float f4v;      // fp32 x4 acc
typedef __attribute__((ext_vector_type(4))) unsigned int u4v;
typedef __attribute__((ext_vector_type(4))) float fl4;

__device__ __forceinline__ unsigned short f2bf(float x) {
    unsigned int u = __float_as_uint(x);
    u = (u + 0x7FFFu + ((u >> 16) & 1u)) >> 16;   // round-to-nearest-even
    return (unsigned short)u;
}
__device__ __forceinline__ float bf2fs(short v) {
    return __uint_as_float(((unsigned int)(unsigned short)v) << 16);
}

// hw packed f32->bf16 (RNE); low16 = src0, high16 = src1
__device__ __forceinline__ unsigned int cvtpk(float lo, float hi) {
    unsigned int r;
    asm("v_cvt_pk_bf16_f32 %0, %1, %2" : "=v"(r) : "v"(lo), "v"(hi));
    return r;
}

__device__ __forceinline__ s8v pack8(fl4 d0, fl4 d1) {
    union { u4v u; s8v s; } cv;
    cv.u[0] = cvtpk(d0[0], d0[1]);
    cv.u[1] = cvtpk(d0[2], d0[3]);
    cv.u[2] = cvtpk(d1[0], d1[1]);
    cv.u[3] = cvtpk(d1[2], d1[3]);
    return cv.s;
}

__device__ __forceinline__ float bflo(unsigned int u) { return __uint_as_float(u << 16); }
__device__ __forceinline__ float bfhi(unsigned int u) { return __uint_as_float(u & 0xffff0000u); }

// Prologue: Mcat[n=h*128+k2][k1] = (1/sqrt128) sum_c Wq[c*4+h][k1] Wk[c*4+h][k2]
//           Pcat[m][kk=h*128+k]  = sum_c Wo[m][c*4+h] Wv[c*4+h][k]
__global__ __launch_bounds__(256) void build_weights(
        const float* __restrict__ Wq, const float* __restrict__ Wk,
        const float* __restrict__ Wv, const float* __restrict__ Wo,
        unsigned short* __restrict__ mcat, unsigned short* __restrict__ pcat) {
    int b = blockIdx.x;
    if (b < 256) {
        int idx = b * 256 + threadIdx.x;
        int n = idx >> 7, k1 = idx & 127;
        int h = n >> 7, k2 = n & 127;
        float s = 0.f;
        #pragma unroll 8
        for (int c = 0; c < 64; c++) {
            int r = c * 4 + h;
            s += Wq[r * 128 + k1] * Wk[r * 128 + k2];
        }
        mcat[idx] = f2bf(s * 0.088388347648318447f);
    } else {
        int idx = (b - 256) * 256 + threadIdx.x;
        int m = idx >> 9, kk = idx & 511;
        int h = kk >> 7, k = kk & 127;
        float s = 0.f;
        #pragma unroll 8
        for (int c = 0; c < 64; c++) {
            int r = c * 4 + h;
            s += Wo[m * 256 + r] * Wv[r * 128 + k];
        }
        pcat[idx] = f2bf(s);
    }
}

// ======================= Kernel S: scores + softmax =======================
// Grid 256 x 512 threads (8 waves), 32 px per wave (2 its of 16).
// LDS: mcat [512][136].  Staged once, one barrier, then free-run.
// Loops it and cb-pair are ROLLED (code-size experiment); h/ks/t unrolled.
#define S_USH (512 * 136)                        // 69632 ush = 139,264 B

__global__ __launch_bounds__(512, 2) void score_kernel(
    const float* __restrict__ z2d, const float* __restrict__ t2d,
    const unsigned short* __restrict__ mcat, float* __restrict__ wbuf) {

    __shared__ unsigned short sm[S_USH];
    const int tid = threadIdx.x;

    // stage mcat (coalesced 16B units) — once per WG (16 units per 128-ush row)
    #pragma unroll
    for (int i = 0; i < 16; i++) {
        int g8 = i * 512 + tid;                  // 16B-unit index, 8192 total
        int row = g8 >> 4, c8 = g8 & 15;
        *(u4v*)&sm[row * 136 + c8 * 8] = *(const u4v*)(mcat + (size_t)g8 * 8);
    }
    __syncthreads();   // the only barrier

    const int wv = tid >> 6, lane = tid & 63, quad = lane >> 4, l15 = lane & 15;

    #pragma unroll 1
    for (int it = 0; it < 2; it++) {
        const int p = blockIdx.x * 256 + (wv * 2 + it) * 16 + l15;

        // z fragments: B-operand (col = pixel = l15, k1 = ks*32 + quad*8 + j)
        s8v za[4];
        {
            const float* zp = z2d + (size_t)p * 128 + quad * 8;
            #pragma unroll
            for (int ks = 0; ks < 4; ks++)
                za[ks] = pack8(*(const fl4*)(zp + ks * 32), *(const fl4*)(zp + ks * 32 + 4));
        }

        float ps[4][4];                          // [h][t] score accumulators
        #pragma unroll
        for (int h = 0; h < 4; h++)
            #pragma unroll
            for (int t = 0; t < 4; t++) ps[h][t] = 0.f;

        const float* apb = t2d + (size_t)p * 128 + quad * 4;

        #pragma unroll 1
        for (int cb2 = 0; cb2 < 8; cb2 += 2) {   // rolled cb-pair loop
            // a_t slices for cb2 and cb2+1 (the pair covers 128B per pixel)
            unsigned int a2[2][4][2];
            #pragma unroll
            for (int u = 0; u < 2; u++)
                #pragma unroll
                for (int t = 0; t < 4; t++) {
                    const fl4 v = *(const fl4*)(apb + (size_t)t * (PIX * 128)
                                                + (cb2 + u) * 16);
                    a2[u][t][0] = cvtpk(v[0], v[1]);
                    a2[u][t][1] = cvtpk(v[2], v[3]);
                }
            #pragma unroll
            for (int u = 0; u < 2; u++) {
                const int rowb = ((cb2 + u) * 16 + l15) * 136 + quad * 8;
                #pragma unroll
                for (int h = 0; h < 4; h++) {
                    f4v uacc = {0.f, 0.f, 0.f, 0.f};
                    #pragma unroll
                    for (int ks = 0; ks < 4; ks++) {
                        const s8v a = *(const s8v*)&sm[h * (128 * 136) + rowb + ks * 32];
                        uacc = __builtin_amdgcn_mfma_f32_16x16x32_bf16(a, za[ks], uacc, 0, 0, 0);
                    }
                    #pragma unroll
                    for (int t = 0; t < 4; t++) {
                        ps[h][t] += uacc[0] * bflo(a2[u][t][0]) + uacc[1] * bfhi(a2[u][t][0])
                                  + uacc[2] * bflo(a2[u][t][1]) + uacc[3] * bfhi(a2[u][t][1]);
                    }
                }
            }
        }

        #pragma unroll
        for (int h = 0; h < 4; h++) {
            // reduce across the 4 quads (same l15) -> full score in every lane
            float s0 = ps[h][0], s1 = ps[h][1], s2 = ps[h][2], s3 = ps[h][3];
            s0 += __shfl_xor(s0, 16); s0 += __shfl_xor(s0, 32);
            s1 += __shfl_xor(s1, 16); s1 += __shfl_xor(s1, 32);
            s2 += __shfl_xor(s2, 16); s2 += __shfl_xor(s2, 32);
            s3 += __shfl_xor(s3, 16); s3 += __shfl_xor(s3, 32);
            const float mx = fmaxf(fmaxf(s0, s1), fmaxf(s2, s3));
            const float e0 = __expf(s0 - mx), e1 = __expf(s1 - mx);
            const float e2 = __expf(s2 - mx), e3 = __expf(s3 - mx);
            const float inv = 1.f / (e0 + e1 + e2 + e3);
            if (quad == 0) {
                float* wp = wbuf + (size_t)h * 4 * PIX + p;
                wp[0 * PIX] = e0 * inv; wp[1 * PIX] = e1 * inv;
                wp[2 * PIX] = e2 * inv; wp[3 * PIX] = e3 * inv;
            }
        }
    }
}

// ======================= Kernel O: Abar + output GEMM =======================
// (byte-identical to round-10/12's measured ~38 us kernel — CONTROL)
// LDS: pcat [128][520] (stride 260 words = 4 mod 32)
#define O_USH (128 * 520)                        // 66560 ush = 133,120 B

__global__ __launch_bounds__(512, 2) void out_kernel(
    const float* __restrict__ t2d, const unsigned short* __restrict__ pcat,
    const float* __restrict__ wbuf, const float* __restrict__ bo,
    float* __restrict__ out) {

    __shared__ unsigned short sm[O_USH];
    const int tid = threadIdx.x;

    // stage pcat — once per WG (512-ush row = 64 x 16B units)
    #pragma unroll
    for (int i = 0; i < 16; i++) {
        int g8 = i * 512 + tid;                  // 8192 x 16B
        int row = g8 >> 6, c8 = g8 & 63;
        *(u4v*)&sm[row * 520 + c8 * 8] = *(const u4v*)(pcat + (size_t)g8 * 8);
    }
    __syncthreads();   // the only barrier

    const int wv = tid >> 6, lane = tid & 63, quad = lane >> 4, l15 = lane & 15;
    const int p0 = blockIdx.x * 256 + wv * 32;   // 32 px per wave

    // softmax weights for this wave's 32 pixels
    float wgt[4][2][4];                          // [t][mt][h]
    #pragma unroll
    for (int h = 0; h < 4; h++)
        #pragma unroll
        for (int t = 0; t < 4; t++)
            #pragma unroll
            for (int mt = 0; mt < 2; mt++)
                wgt[t][mt][h] = wbuf[(size_t)(h * 4 + t) * PIX + p0 + mt * 16 + l15];

    f4v acc[2][8];
    #pragma unroll
    for (int mt = 0; mt < 2; mt++)
        #pragma unroll
        for (int ct = 0; ct < 8; ct++) acc[mt][ct] = (f4v){0.f, 0.f, 0.f, 0.f};

    #pragma unroll
    for (int ks = 0; ks < 4; ks++) {             // K-within-head, outer
        // t2d slices for this ks (4t x 2mt), fp32 -> bf16 regs
        s8v ab[4][2];
        #pragma unroll
        for (int t = 0; t < 4; t++)
            #pragma unroll
            for (int mt = 0; mt < 2; mt++) {
                const float* ap = t2d + ((size_t)t * PIX + p0 + mt * 16 + l15) * 128
                                  + ks * 32 + quad * 8;
                const fl4 d0 = *(const fl4*)ap;
                const fl4 d1 = *(const fl4*)(ap + 4);
                s8v a;
                a[0] = (short)f2bf(d0[0]); a[1] = (short)f2bf(d0[1]);
                a[2] = (short)f2bf(d0[2]); a[3] = (short)f2bf(d0[3]);
                a[4] = (short)f2bf(d1[0]); a[5] = (short)f2bf(d1[1]);
                a[6] = (short)f2bf(d1[2]); a[7] = (short)f2bf(d1[3]);
                ab[t][mt] = a;
            }
        #pragma unroll
        for (int h = 0; h < 4; h++) {
            // Abar A-frags in registers
            s8v af[2];
            #pragma unroll
            for (int mt = 0; mt < 2; mt++) {
                s8v o;
                #pragma unroll
                for (int j = 0; j < 8; j++) {
                    float v = wgt[0][mt][h] * bf2fs(ab[0][mt][j])
                            + wgt[1][mt][h] * bf2fs(ab[1][mt][j])
                            + wgt[2][mt][h] * bf2fs(ab[2][mt][j])
                            + wgt[3][mt][h] * bf2fs(ab[3][mt][j]);
                    o[j] = (short)f2bf(v);
                }
                af[mt] = o;
            }
            #pragma unroll
            for (int ct = 0; ct < 8; ct++) {
                const s8v b = *(const s8v*)&sm[(ct * 16 + l15) * 520
                                               + h * 128 + ks * 32 + quad * 8];
                acc[0][ct] = __builtin_amdgcn_mfma_f32_16x16x32_bf16(af[0], b, acc[0][ct], 0, 0, 0);
                acc[1][ct] = __builtin_amdgcn_mfma_f32_16x16x32_bf16(af[1], b, acc[1][ct], 0, 0, 0);
            }
        }
    }

    // epilogue: bias + fp32 store
    #pragma unroll
    for (int ct = 0; ct < 8; ct++) {
        const float bb = bo[ct * 16 + l15];
        #pragma unroll
        for (int mt = 0; mt < 2; mt++)
            #pragma unroll
            for (int r = 0; r < 4; r++)
                out[(size_t)(p0 + mt * 16 + quad * 4 + r) * 128 + ct * 16 + l15]
                    = acc[mt][ct][r] + bb;
    }
}

extern "C" void kernel_launch(void* const* d_in, const int* in_sizes, int n_in,
                              void* d_out, int out_size, void* d_ws, size_t ws_size,
                              hipStream_t stream) {
    const float* z2d = (const float*)d_in[0];
    const float* t2d = (const float*)d_in[1];
    const float* Wq  = (const float*)d_in[2];
    const float* Wk  = (const float*)d_in[3];
    const float* Wv  = (const float*)d_in[4];
    const float* Wo  = (const float*)d_in[5];
    const float* bo  = (const float*)d_in[6];

    unsigned short* mcat = (unsigned short*)d_ws;          // 512*128 bf16 = 128 KB
    unsigned short* pcat = mcat + 512 * 128;               // 128*512 bf16 = 128 KB
    float* wbuf = (float*)(pcat + 128 * 512);              // 16*65536 fp32 = 4 MB

    build_weights<<<512, 256, 0, stream>>>(Wq, Wk, Wv, Wo, mcat, pcat);
    score_kernel<<<256, 512, 0, stream>>>(z2d, t2d, mcat, wbuf);
    out_kernel<<<256, 512, 0, stream>>>(t2d, pcat, wbuf, bo, (float*)d_out);
}